// Round 15
// baseline (2027.020 us; speedup 1.0000x reference)
//
#include <hip/hip_runtime.h>

#define N_VEC   32768      // 32*1024
#define K_CODES 4096
#define D_DIM   64
#define NELEM   2097152    // N_VEC * D_DIM
#define TH_APPROX 7.5e-4f

// ---- output layout (floats, concatenated in reference return order) ----
#define OUT0_OFF 0           // quantized_st  (2097152)
#define OUT1_OFF 2097152     // loss          (1)
#define OUT2_OFF 2097153     // indices       (32768)
#define OUT3_OFF 2129921     // new_weight    (262144)
#define OUT4_OFF 2392065     // ema_cs        (4096)
#define OUT5_OFF 2396161     // ema_es        (262144)

// ---- ws layout. SUMS overlays WBF (dead after k_score); memset after. ---
#define WS_BNORM   0            // float[4096]       (16384)
#define WS_COUNTS  16384        // int[4096]         (16384)
#define WS_CANDC   32768        // int[32768]        (131072)
#define WS_CANDS   163840       // ushort[32768*16]  (1048576)
#define WS_WBF     1212416      // short[262144]     (524288)  dead after k_score
#define WS_SUMS    1212416      // float[262144]     (1048576) overlay, memset later
#define WS_LPART   2260992      // double[8192]      (65536)
#define WS_CSPART  2326528      // double[16]        (128)
// total 2326656 B

typedef short  s16x8 __attribute__((ext_vector_type(8)));
typedef float  f32x4 __attribute__((ext_vector_type(4)));
typedef unsigned short u16x8 __attribute__((ext_vector_type(8)));

__device__ __forceinline__ unsigned short bf16rne(float f) {
    unsigned u = __float_as_uint(f);
    unsigned r = u + 0x7fffu + ((u >> 16) & 1u);
    return (unsigned short)(r >> 16);
}

// numpy pairwise_sum base case (n=64): 8 accumulators strided by 8,
// sequential adds, fixed combine tree. sq[] must be PRE-ROUNDED squares.
__device__ __forceinline__ float np_pairwise64(const float* sq) {
    float r0 = sq[0], r1 = sq[1], r2 = sq[2], r3 = sq[3];
    float r4 = sq[4], r5 = sq[5], r6 = sq[6], r7 = sq[7];
#pragma unroll
    for (int b = 8; b < 64; b += 8) {
        r0 = __fadd_rn(r0, sq[b + 0]); r1 = __fadd_rn(r1, sq[b + 1]);
        r2 = __fadd_rn(r2, sq[b + 2]); r3 = __fadd_rn(r3, sq[b + 3]);
        r4 = __fadd_rn(r4, sq[b + 4]); r5 = __fadd_rn(r5, sq[b + 5]);
        r6 = __fadd_rn(r6, sq[b + 6]); r7 = __fadd_rn(r7, sq[b + 7]);
    }
    return __fadd_rn(__fadd_rn(__fadd_rn(r0, r1), __fadd_rn(r2, r3)),
                     __fadd_rn(__fadd_rn(r4, r5), __fadd_rn(r6, r7)));
}

// ---- fused: bn = np-exact ||w_k||^2, wbf = bf16(w), zero counts/candc ---
__global__ void k_prep(const float* __restrict__ w, float* __restrict__ bn,
                       short* __restrict__ wbf, int* __restrict__ counts,
                       int* __restrict__ candc) {
    const int k = blockIdx.x * 256 + threadIdx.x;   // 0..4095
    counts[k] = 0;
#pragma unroll
    for (int i = 0; i < 8; ++i) candc[k * 8 + i] = 0;

    const float4* wr = (const float4*)(w + (size_t)k * D_DIM);
    float4 v[16];
#pragma unroll
    for (int i = 0; i < 16; ++i) v[i] = wr[i];
    float sq[64];
#pragma unroll
    for (int i = 0; i < 16; ++i) {
        sq[4*i+0] = __fmul_rn(v[i].x, v[i].x);
        sq[4*i+1] = __fmul_rn(v[i].y, v[i].y);
        sq[4*i+2] = __fmul_rn(v[i].z, v[i].z);
        sq[4*i+3] = __fmul_rn(v[i].w, v[i].w);
    }
    bn[k] = np_pairwise64(sq);
#pragma unroll
    for (int i = 0; i < 8; ++i) {
        u16x8 o;
        o[0] = bf16rne(v[2*i].x);   o[1] = bf16rne(v[2*i].y);
        o[2] = bf16rne(v[2*i].z);   o[3] = bf16rne(v[2*i].w);
        o[4] = bf16rne(v[2*i+1].x); o[5] = bf16rne(v[2*i+1].y);
        o[6] = bf16rne(v[2*i+1].z); o[7] = bf16rne(v[2*i+1].w);
        *(u16x8*)&wbf[(size_t)k * D_DIM + i * 8] = o;
    }
}

// ======== single-kernel MFMA prefilter (sweep-min + collect) =============
// Grid 2048: rg = blockIdx&511 (64 rows), kc = blockIdx>>9 (1024-col chunk).
// Superset property: {m <= gmin+TH} subset of {m <= chunkmin+TH} since
// chunkmin >= gmin -> collecting vs the block's own chunk-min is correct.
// Depth-2 pipeline with NAMED regs (R13's array staging spilled: 102 MB
// scratch writes). mfma_f32_16x16x32_bf16: A row=l&15, k=(l>>4)*8+e;
// B col=l&15; C col=l&15, row=(l>>4)*4+reg (m89-verified, R9-validated).
#define XLDS_LD 72

#define LOADT(pa, pb, pn, T)                                                \
    {   const int c_ = col0 + (T) * 16 + arow;                              \
        pa = *(const s16x8*)&wbf[(size_t)c_ * D_DIM + agrp * 8];            \
        pb = *(const s16x8*)&wbf[(size_t)c_ * D_DIM + 32 + agrp * 8];       \
        pn = bn[c_];                                                        \
    }

#define COMP_MIN(pa, pb, pn)                                                \
    _Pragma("unroll")                                                       \
    for (int rt = 0; rt < 4; ++rt) {                                        \
        f32x4 c = {0.f, 0.f, 0.f, 0.f};                                     \
        c = __builtin_amdgcn_mfma_f32_16x16x32_bf16(af0[rt], pa, c, 0, 0, 0); \
        c = __builtin_amdgcn_mfma_f32_16x16x32_bf16(af1[rt], pb, c, 0, 0, 0); \
        _Pragma("unroll")                                                   \
        for (int j = 0; j < 4; ++j) {                                       \
            float m = fmaf(-2.0f, c[j], pn);                                \
            rm[rt * 4 + j] = fminf(rm[rt * 4 + j], m);                      \
        }                                                                   \
    }

#define COMP_COL(pa, pb, pn, T)                                             \
    _Pragma("unroll")                                                       \
    for (int rt = 0; rt < 4; ++rt) {                                        \
        f32x4 c = {0.f, 0.f, 0.f, 0.f};                                     \
        c = __builtin_amdgcn_mfma_f32_16x16x32_bf16(af0[rt], pa, c, 0, 0, 0); \
        c = __builtin_amdgcn_mfma_f32_16x16x32_bf16(af1[rt], pb, c, 0, 0, 0); \
        _Pragma("unroll")                                                   \
        for (int j = 0; j < 4; ++j) {                                       \
            float m = fmaf(-2.0f, c[j], pn);                                \
            if (m <= gv[rt * 4 + j]) {                                      \
                int n_ = rbase + rt * 16 + agrp * 4 + j;                    \
                int p_ = atomicAdd(&candc[n_], 1);                          \
                if (p_ < 16)                                                \
                    cands[(size_t)n_ * 16 + p_] =                           \
                        (unsigned short)(col0 + (T) * 16 + arow);           \
            }                                                               \
        }                                                                   \
    }

__global__ __launch_bounds__(256, 4) void k_score(
    const float* __restrict__ x, const short* __restrict__ wbf,
    const float* __restrict__ bn, int* __restrict__ candc,
    unsigned short* __restrict__ cands) {
    __shared__ short xlds[64 * XLDS_LD];
    __shared__ float wmin[4][64];
    __shared__ float gmin[64];

    const int tid  = threadIdx.x;
    const int lane = tid & 63;
    const int wid  = __builtin_amdgcn_readfirstlane(tid >> 6);
    const int rg   = blockIdx.x & 511;
    const int kc   = blockIdx.x >> 9;
    const int rbase = rg * 64;
    const int arow = lane & 15;
    const int agrp = lane >> 4;

    // stage x rows -> bf16 LDS
    for (int i = tid; i < 64 * 16; i += 256) {
        int r = i >> 4, c4 = i & 15;
        float4 v = ((const float4*)(x + (size_t)(rbase + r) * D_DIM))[c4];
        ushort4 b;
        b.x = bf16rne(v.x); b.y = bf16rne(v.y);
        b.z = bf16rne(v.z); b.w = bf16rne(v.w);
        *(ushort4*)&xlds[r * XLDS_LD + c4 * 4] = b;
    }
    __syncthreads();

    // hoist A-frags (const-indexed arrays: register-resident, R9-proven)
    s16x8 af0[4], af1[4];
#pragma unroll
    for (int rt = 0; rt < 4; ++rt) {
        af0[rt] = *(const s16x8*)&xlds[(rt * 16 + arow) * XLDS_LD + agrp * 8];
        af1[rt] = *(const s16x8*)&xlds[(rt * 16 + arow) * XLDS_LD + 32 + agrp * 8];
    }

    const int col0 = kc * 1024 + wid * 256;

    s16x8 ea0, ea1; float ebn;
    s16x8 va0, va1; float vbn;

    // ---- sweep 1: chunk-min, depth-2 pipelined --------------------------
    float rm[16];
#pragma unroll
    for (int i = 0; i < 16; ++i) rm[i] = 3.4e38f;

    LOADT(ea0, ea1, ebn, 0)
    LOADT(va0, va1, vbn, 1)
#pragma unroll
    for (int tp = 0; tp < 7; ++tp) {
        COMP_MIN(ea0, ea1, ebn)
        LOADT(ea0, ea1, ebn, 2 * tp + 2)
        COMP_MIN(va0, va1, vbn)
        LOADT(va0, va1, vbn, 2 * tp + 3)
    }
    COMP_MIN(ea0, ea1, ebn)
    COMP_MIN(va0, va1, vbn)

    // cross-col (lane&15) min, then cross-wave min via LDS (R9-verified)
#pragma unroll
    for (int i = 0; i < 16; ++i) {
        float v = rm[i];
        v = fminf(v, __shfl_xor(v, 1));
        v = fminf(v, __shfl_xor(v, 2));
        v = fminf(v, __shfl_xor(v, 4));
        v = fminf(v, __shfl_xor(v, 8));
        rm[i] = v;
    }
    if (arow == 0) {
#pragma unroll
        for (int i = 0; i < 16; ++i)
            wmin[wid][(i >> 2) * 16 + agrp * 4 + (i & 3)] = rm[i];
    }
    __syncthreads();
    if (tid < 64) {
        float g = fminf(fminf(wmin[0][tid], wmin[1][tid]),
                        fminf(wmin[2][tid], wmin[3][tid]));
        gmin[tid] = g + TH_APPROX;
    }
    __syncthreads();

    float gv[16];
#pragma unroll
    for (int i = 0; i < 16; ++i)
        gv[i] = gmin[(i >> 2) * 16 + agrp * 4 + (i & 3)];

    // ---- sweep 2: recompute (chunk L2-hot), collect vs chunkmin+TH ------
    LOADT(ea0, ea1, ebn, 0)
    LOADT(va0, va1, vbn, 1)
#pragma unroll
    for (int tp = 0; tp < 7; ++tp) {
        COMP_COL(ea0, ea1, ebn, 2 * tp)
        LOADT(ea0, ea1, ebn, 2 * tp + 2)
        COMP_COL(va0, va1, vbn, 2 * tp + 1)
        LOADT(va0, va1, vbn, 2 * tp + 3)
    }
    COMP_COL(ea0, ea1, ebn, 14)
    COMP_COL(va0, va1, vbn, 15)
}

// -------- exact np rescore of the shortlist (index only) -----------------
__global__ __launch_bounds__(256) void k_rescore(
    const float* __restrict__ x, const float* __restrict__ w,
    const float* __restrict__ bn, const int* __restrict__ candc,
    const unsigned short* __restrict__ cands, float* __restrict__ out_idx) {
    const int n = blockIdx.x * 256 + threadIdx.x;

    float4 xv[16];
    const float4* xr = (const float4*)(x + (size_t)n * D_DIM);
#pragma unroll
    for (int i = 0; i < 16; ++i) xv[i] = xr[i];

    // A_n: numpy-exact sum of pre-rounded squares
    float A;
    {
        float sq[64];
#pragma unroll
        for (int i = 0; i < 16; ++i) {
            sq[4*i+0] = __fmul_rn(xv[i].x, xv[i].x);
            sq[4*i+1] = __fmul_rn(xv[i].y, xv[i].y);
            sq[4*i+2] = __fmul_rn(xv[i].z, xv[i].z);
            sq[4*i+3] = __fmul_rn(xv[i].w, xv[i].w);
        }
        A = np_pairwise64(sq);
    }

    const int cnt = candc[n];
    float bestd = 3.4e38f;
    int   besti = 0;

    if (cnt <= 16) {
        unsigned short cl[16];
        for (int i = 0; i < cnt; ++i) cl[i] = cands[(size_t)n * 16 + i];
        // sort ascending so strict < reproduces np first-min tie-break
        for (int i = 1; i < cnt; ++i) {
            unsigned short v = cl[i];
            int j = i - 1;
            while (j >= 0 && cl[j] > v) { cl[j + 1] = cl[j]; --j; }
            cl[j + 1] = v;
        }
        for (int i = 0; i < cnt; ++i) {
            const int c = cl[i];
            const float4* wr = (const float4*)(w + (size_t)c * D_DIM);
            float a = 0.f;
#pragma unroll
            for (int ch = 0; ch < 16; ++ch) {
                float4 u = wr[ch];
                a = __fmaf_rn(xv[ch].x, u.x, a);
                a = __fmaf_rn(xv[ch].y, u.y, a);
                a = __fmaf_rn(xv[ch].z, u.z, a);
                a = __fmaf_rn(xv[ch].w, u.w, a);
            }
            float d = __fsub_rn(__fadd_rn(A, bn[c]), __fmul_rn(2.0f, a));
            if (d < bestd) { bestd = d; besti = c; }
        }
    } else {
        // overflow fallback: full exact np scan (P ~ 0)
        for (int c = 0; c < K_CODES; ++c) {
            const float4* wr = (const float4*)(w + (size_t)c * D_DIM);
            float a = 0.f;
#pragma unroll
            for (int ch = 0; ch < 16; ++ch) {
                float4 u = wr[ch];
                a = __fmaf_rn(xv[ch].x, u.x, a);
                a = __fmaf_rn(xv[ch].y, u.y, a);
                a = __fmaf_rn(xv[ch].z, u.z, a);
                a = __fmaf_rn(xv[ch].w, u.w, a);
            }
            float d = __fsub_rn(__fadd_rn(A, bn[c]), __fmul_rn(2.0f, a));
            if (d < bestd) { bestd = d; besti = c; }
        }
    }
    out_idx[n] = (float)besti;
}

// ---- gather + STE + loss partials + segment sums (element-per-thread, ---
// ---- coalesced: R14's row-per-thread fusion was 13x slower)          ---
__global__ __launch_bounds__(256) void k_quant(
    const float* __restrict__ x, const float* __restrict__ w,
    const float* __restrict__ idxf, float* __restrict__ out0,
    float* __restrict__ sums, int* __restrict__ counts,
    double* __restrict__ lpart) {
    const int gid = blockIdx.x * 256 + threadIdx.x;
    const int n = gid >> 6, d = gid & 63;
    const int idx = (int)idxf[n];
    const float in = x[gid];
    const float q  = w[idx * D_DIM + d];
    out0[gid] = in + (q - in);               // straight-through
    const float diff = in - q;
    atomicAdd(&sums[idx * D_DIM + d], in);
    if (d == 0) atomicAdd(&counts[idx], 1);

    __shared__ double red[256];
    red[threadIdx.x] = (double)diff * (double)diff;
    __syncthreads();
    for (int s = 128; s > 0; s >>= 1) {
        if (threadIdx.x < s) red[threadIdx.x] += red[threadIdx.x + s];
        __syncthreads();
    }
    if (threadIdx.x == 0) lpart[blockIdx.x] = red[0];
}

// -------------------- loss finalize (deterministic) ----------------------
__global__ void k_loss(const double* __restrict__ lpart, float* __restrict__ out1) {
    __shared__ double red[256];
    double s = 0.0;
    for (int i = threadIdx.x; i < 8192; i += 256) s += lpart[i];
    red[threadIdx.x] = s;
    __syncthreads();
    for (int st = 128; st > 0; st >>= 1) {
        if (threadIdx.x < st) red[threadIdx.x] += red[threadIdx.x + st];
        __syncthreads();
    }
    if (threadIdx.x == 0) out1[0] = (float)(0.25 * red[0] / (double)NELEM);
}

// -------------------- ema_cs + partial sums for n ------------------------
__global__ void k_emacs(const float* __restrict__ old_cs, const int* __restrict__ counts,
                        float* __restrict__ out4, double* __restrict__ cspart) {
    const int k = blockIdx.x * 256 + threadIdx.x;
    const float e = 0.99f * old_cs[k] + 0.01f * (float)counts[k];
    out4[k] = e;
    __shared__ double red[256];
    red[threadIdx.x] = (double)e;
    __syncthreads();
    for (int s = 128; s > 0; s >>= 1) {
        if (threadIdx.x < s) red[threadIdx.x] += red[threadIdx.x + s];
        __syncthreads();
    }
    if (threadIdx.x == 0) cspart[blockIdx.x] = red[0];
}

// -------------------- ema_es + new_weight --------------------------------
__global__ __launch_bounds__(256) void k_final(
    const float* __restrict__ old_es, const float* __restrict__ sums,
    const float* __restrict__ out4, const double* __restrict__ cspart,
    float* __restrict__ out3, float* __restrict__ out5) {
    double nd = 0.0;
#pragma unroll
    for (int i = 0; i < 16; ++i) nd += cspart[i];
    const float nf = (float)nd;
    const int gid = blockIdx.x * 256 + threadIdx.x;
    const int k = gid >> 6;
    const float es = 0.99f * old_es[gid] + 0.01f * sums[gid];
    out5[gid] = es;
    const float cs = out4[k];
    const float cssm = (cs + 1e-5f) / (nf + 4096.0f * 1e-5f) * nf;
    out3[gid] = es / cssm;
}

extern "C" void kernel_launch(void* const* d_in, const int* in_sizes, int n_in,
                              void* d_out, int out_size, void* d_ws, size_t ws_size,
                              hipStream_t stream) {
    const float* x      = (const float*)d_in[0];
    const float* w      = (const float*)d_in[1];
    const float* old_cs = (const float*)d_in[2];
    const float* old_es = (const float*)d_in[3];

    float* o    = (float*)d_out;
    float* out0 = o + OUT0_OFF;
    float* out1 = o + OUT1_OFF;
    float* out2 = o + OUT2_OFF;
    float* out3 = o + OUT3_OFF;
    float* out4 = o + OUT4_OFF;
    float* out5 = o + OUT5_OFF;

    char* ws = (char*)d_ws;
    float*          bnorm  = (float*)(ws + WS_BNORM);
    int*            counts = (int*)(ws + WS_COUNTS);
    int*            candc  = (int*)(ws + WS_CANDC);
    unsigned short* cands  = (unsigned short*)(ws + WS_CANDS);
    short*          wbf    = (short*)(ws + WS_WBF);
    float*          sums   = (float*)(ws + WS_SUMS);
    double*         lpart  = (double*)(ws + WS_LPART);
    double*         cspart = (double*)(ws + WS_CSPART);

    k_prep<<<K_CODES / 256, 256, 0, stream>>>(w, bnorm, wbf, counts, candc);
    k_score<<<2048, 256, 0, stream>>>(x, wbf, bnorm, candc, cands);
    // sums overlays wbf (dead after k_score): zero it now, before k_quant
    hipMemsetAsync(sums, 0, K_CODES * D_DIM * sizeof(float), stream);
    k_rescore<<<N_VEC / 256, 256, 0, stream>>>(x, w, bnorm, candc, cands, out2);
    k_quant<<<NELEM / 256, 256, 0, stream>>>(x, w, out2, out0, sums, counts, lpart);
    k_loss<<<1, 256, 0, stream>>>(lpart, out1);
    k_emacs<<<K_CODES / 256, 256, 0, stream>>>(old_cs, counts, out4, cspart);
    k_final<<<K_CODES * D_DIM / 256, 256, 0, stream>>>(old_es, sums, out4, cspart,
                                                       out3, out5);
}

// Round 16
// 168.735 us; speedup vs baseline: 12.0130x; 12.0130x over previous
//
#include <hip/hip_runtime.h>

#define N_VEC   32768      // 32*1024
#define K_CODES 4096
#define D_DIM   64
#define NELEM   2097152    // N_VEC * D_DIM
#define TH_APPROX 7.5e-4f
#define CAP     32

// ---- output layout (floats, concatenated in reference return order) ----
#define OUT0_OFF 0           // quantized_st  (2097152)
#define OUT1_OFF 2097152     // loss          (1)
#define OUT2_OFF 2097153     // indices       (32768)
#define OUT3_OFF 2129921     // new_weight    (262144)
#define OUT4_OFF 2392065     // ema_cs        (4096)
#define OUT5_OFF 2396161     // ema_es        (262144)

// ---- ws layout. SUMS overlays WBF (dead after k_score); memset after. ---
#define WS_BNORM   0            // float[4096]        (16384)
#define WS_COUNTS  16384        // int[4096]          (16384)
#define WS_CANDC   32768        // int[32768]         (131072)
#define WS_CANDS   163840       // ushort[32768*32]   (2097152)
#define WS_WBF     2260992      // short[262144]      (524288)  dead after k_score
#define WS_SUMS    2260992      // float[262144]      (1048576) overlay, memset later
#define WS_LPART   3309568      // double[8192]       (65536)
#define WS_CSPART  3375104      // double[16]         (128)
// total 3375232 B

typedef short  s16x8 __attribute__((ext_vector_type(8)));
typedef float  f32x4 __attribute__((ext_vector_type(4)));
typedef unsigned short u16x8 __attribute__((ext_vector_type(8)));

__device__ __forceinline__ unsigned short bf16rne(float f) {
    unsigned u = __float_as_uint(f);
    unsigned r = u + 0x7fffu + ((u >> 16) & 1u);
    return (unsigned short)(r >> 16);
}

// numpy pairwise_sum base case (n=64): 8 accumulators strided by 8,
// sequential adds, fixed combine tree. sq[] must be PRE-ROUNDED squares.
__device__ __forceinline__ float np_pairwise64(const float* sq) {
    float r0 = sq[0], r1 = sq[1], r2 = sq[2], r3 = sq[3];
    float r4 = sq[4], r5 = sq[5], r6 = sq[6], r7 = sq[7];
#pragma unroll
    for (int b = 8; b < 64; b += 8) {
        r0 = __fadd_rn(r0, sq[b + 0]); r1 = __fadd_rn(r1, sq[b + 1]);
        r2 = __fadd_rn(r2, sq[b + 2]); r3 = __fadd_rn(r3, sq[b + 3]);
        r4 = __fadd_rn(r4, sq[b + 4]); r5 = __fadd_rn(r5, sq[b + 5]);
        r6 = __fadd_rn(r6, sq[b + 6]); r7 = __fadd_rn(r7, sq[b + 7]);
    }
    return __fadd_rn(__fadd_rn(__fadd_rn(r0, r1), __fadd_rn(r2, r3)),
                     __fadd_rn(__fadd_rn(r4, r5), __fadd_rn(r6, r7)));
}

// np-exact distance for one codeword c given register x row + A
__device__ __forceinline__ float np_dist(const float4* __restrict__ xv, float A,
                                         const float* __restrict__ w,
                                         const float* __restrict__ bn, int c) {
    const float4* wr = (const float4*)(w + (size_t)c * D_DIM);
    float a = 0.f;
#pragma unroll
    for (int ch = 0; ch < 16; ++ch) {
        float4 u = wr[ch];
        a = __fmaf_rn(xv[ch].x, u.x, a);
        a = __fmaf_rn(xv[ch].y, u.y, a);
        a = __fmaf_rn(xv[ch].z, u.z, a);
        a = __fmaf_rn(xv[ch].w, u.w, a);
    }
    return __fsub_rn(__fadd_rn(A, bn[c]), __fmul_rn(2.0f, a));
}

// ---- fused: bn = np-exact ||w_k||^2, wbf = bf16(w), zero counts/candc ---
__global__ void k_prep(const float* __restrict__ w, float* __restrict__ bn,
                       short* __restrict__ wbf, int* __restrict__ counts,
                       int* __restrict__ candc) {
    const int k = blockIdx.x * 256 + threadIdx.x;   // 0..4095
    counts[k] = 0;
#pragma unroll
    for (int i = 0; i < 8; ++i) candc[k * 8 + i] = 0;

    const float4* wr = (const float4*)(w + (size_t)k * D_DIM);
    float4 v[16];
#pragma unroll
    for (int i = 0; i < 16; ++i) v[i] = wr[i];
    float sq[64];
#pragma unroll
    for (int i = 0; i < 16; ++i) {
        sq[4*i+0] = __fmul_rn(v[i].x, v[i].x);
        sq[4*i+1] = __fmul_rn(v[i].y, v[i].y);
        sq[4*i+2] = __fmul_rn(v[i].z, v[i].z);
        sq[4*i+3] = __fmul_rn(v[i].w, v[i].w);
    }
    bn[k] = np_pairwise64(sq);
#pragma unroll
    for (int i = 0; i < 8; ++i) {
        u16x8 o;
        o[0] = bf16rne(v[2*i].x);   o[1] = bf16rne(v[2*i].y);
        o[2] = bf16rne(v[2*i].z);   o[3] = bf16rne(v[2*i].w);
        o[4] = bf16rne(v[2*i+1].x); o[5] = bf16rne(v[2*i+1].y);
        o[6] = bf16rne(v[2*i+1].z); o[7] = bf16rne(v[2*i+1].w);
        *(u16x8*)&wbf[(size_t)k * D_DIM + i * 8] = o;
    }
}

// ======== single-kernel MFMA prefilter (sweep-min + collect) =============
// Grid 2048: rg = blockIdx&511 (64 rows), kc = blockIdx>>9 (1024-col chunk).
// Superset property: {m <= gmin+TH} subset of {m <= chunkmin+TH}. Collect
// vs own chunk-min is a correct superset; cap CAP=32, overflow -> wave-
// parallel full scan in k_rescore. Depth-2 pipeline, named regs (R13
// array staging spilled). mfma layouts m89-verified, R9-validated.
#define XLDS_LD 72

#define LOADT(pa, pb, pn, T)                                                \
    {   const int c_ = col0 + (T) * 16 + arow;                              \
        pa = *(const s16x8*)&wbf[(size_t)c_ * D_DIM + agrp * 8];            \
        pb = *(const s16x8*)&wbf[(size_t)c_ * D_DIM + 32 + agrp * 8];       \
        pn = bn[c_];                                                        \
    }

#define COMP_MIN(pa, pb, pn)                                                \
    _Pragma("unroll")                                                       \
    for (int rt = 0; rt < 4; ++rt) {                                        \
        f32x4 c = {0.f, 0.f, 0.f, 0.f};                                     \
        c = __builtin_amdgcn_mfma_f32_16x16x32_bf16(af0[rt], pa, c, 0, 0, 0); \
        c = __builtin_amdgcn_mfma_f32_16x16x32_bf16(af1[rt], pb, c, 0, 0, 0); \
        _Pragma("unroll")                                                   \
        for (int j = 0; j < 4; ++j) {                                       \
            float m = fmaf(-2.0f, c[j], pn);                                \
            rm[rt * 4 + j] = fminf(rm[rt * 4 + j], m);                      \
        }                                                                   \
    }

#define COMP_COL(pa, pb, pn, T)                                             \
    _Pragma("unroll")                                                       \
    for (int rt = 0; rt < 4; ++rt) {                                        \
        f32x4 c = {0.f, 0.f, 0.f, 0.f};                                     \
        c = __builtin_amdgcn_mfma_f32_16x16x32_bf16(af0[rt], pa, c, 0, 0, 0); \
        c = __builtin_amdgcn_mfma_f32_16x16x32_bf16(af1[rt], pb, c, 0, 0, 0); \
        _Pragma("unroll")                                                   \
        for (int j = 0; j < 4; ++j) {                                       \
            float m = fmaf(-2.0f, c[j], pn);                                \
            if (m <= gv[rt * 4 + j]) {                                      \
                int n_ = rbase + rt * 16 + agrp * 4 + j;                    \
                int p_ = atomicAdd(&candc[n_], 1);                          \
                if (p_ < CAP)                                               \
                    cands[(size_t)n_ * CAP + p_] =                          \
                        (unsigned short)(col0 + (T) * 16 + arow);           \
            }                                                               \
        }                                                                   \
    }

__global__ __launch_bounds__(256, 4) void k_score(
    const float* __restrict__ x, const short* __restrict__ wbf,
    const float* __restrict__ bn, int* __restrict__ candc,
    unsigned short* __restrict__ cands) {
    __shared__ short xlds[64 * XLDS_LD];
    __shared__ float wmin[4][64];
    __shared__ float gmin[64];

    const int tid  = threadIdx.x;
    const int lane = tid & 63;
    const int wid  = __builtin_amdgcn_readfirstlane(tid >> 6);
    const int rg   = blockIdx.x & 511;
    const int kc   = blockIdx.x >> 9;
    const int rbase = rg * 64;
    const int arow = lane & 15;
    const int agrp = lane >> 4;

    // stage x rows -> bf16 LDS
    for (int i = tid; i < 64 * 16; i += 256) {
        int r = i >> 4, c4 = i & 15;
        float4 v = ((const float4*)(x + (size_t)(rbase + r) * D_DIM))[c4];
        ushort4 b;
        b.x = bf16rne(v.x); b.y = bf16rne(v.y);
        b.z = bf16rne(v.z); b.w = bf16rne(v.w);
        *(ushort4*)&xlds[r * XLDS_LD + c4 * 4] = b;
    }
    __syncthreads();

    // hoist A-frags (const-indexed arrays: register-resident, R9-proven)
    s16x8 af0[4], af1[4];
#pragma unroll
    for (int rt = 0; rt < 4; ++rt) {
        af0[rt] = *(const s16x8*)&xlds[(rt * 16 + arow) * XLDS_LD + agrp * 8];
        af1[rt] = *(const s16x8*)&xlds[(rt * 16 + arow) * XLDS_LD + 32 + agrp * 8];
    }

    const int col0 = kc * 1024 + wid * 256;

    s16x8 ea0, ea1; float ebn;
    s16x8 va0, va1; float vbn;

    // ---- sweep 1: chunk-min, depth-2 pipelined --------------------------
    float rm[16];
#pragma unroll
    for (int i = 0; i < 16; ++i) rm[i] = 3.4e38f;

    LOADT(ea0, ea1, ebn, 0)
    LOADT(va0, va1, vbn, 1)
#pragma unroll
    for (int tp = 0; tp < 7; ++tp) {
        COMP_MIN(ea0, ea1, ebn)
        LOADT(ea0, ea1, ebn, 2 * tp + 2)
        COMP_MIN(va0, va1, vbn)
        LOADT(va0, va1, vbn, 2 * tp + 3)
    }
    COMP_MIN(ea0, ea1, ebn)
    COMP_MIN(va0, va1, vbn)

    // cross-col (lane&15) min, then cross-wave min via LDS (R9-verified)
#pragma unroll
    for (int i = 0; i < 16; ++i) {
        float v = rm[i];
        v = fminf(v, __shfl_xor(v, 1));
        v = fminf(v, __shfl_xor(v, 2));
        v = fminf(v, __shfl_xor(v, 4));
        v = fminf(v, __shfl_xor(v, 8));
        rm[i] = v;
    }
    if (arow == 0) {
#pragma unroll
        for (int i = 0; i < 16; ++i)
            wmin[wid][(i >> 2) * 16 + agrp * 4 + (i & 3)] = rm[i];
    }
    __syncthreads();
    if (tid < 64) {
        float g = fminf(fminf(wmin[0][tid], wmin[1][tid]),
                        fminf(wmin[2][tid], wmin[3][tid]));
        gmin[tid] = g + TH_APPROX;
    }
    __syncthreads();

    float gv[16];
#pragma unroll
    for (int i = 0; i < 16; ++i)
        gv[i] = gmin[(i >> 2) * 16 + agrp * 4 + (i & 3)];

    // ---- sweep 2: recompute (chunk L2-hot), collect vs chunkmin+TH ------
    LOADT(ea0, ea1, ebn, 0)
    LOADT(va0, va1, vbn, 1)
#pragma unroll
    for (int tp = 0; tp < 7; ++tp) {
        COMP_COL(ea0, ea1, ebn, 2 * tp)
        LOADT(ea0, ea1, ebn, 2 * tp + 2)
        COMP_COL(va0, va1, vbn, 2 * tp + 1)
        LOADT(va0, va1, vbn, 2 * tp + 3)
    }
    COMP_COL(ea0, ea1, ebn, 14)
    COMP_COL(va0, va1, vbn, 15)
}

// -------- exact np rescore, ONE WAVE PER ROW -----------------------------
// Lane i evaluates candidate i (x row is wave-uniform -> broadcast loads);
// lexicographic (d, idx) shfl-reduce == np.argmin first-min (smallest
// index among global-min achievers). Overflow: 64 lanes x 64 codewords
// wave-parallel full scan (R15's 1-thread serial fallback was 1944 us at
// 1% occupancy).
__global__ __launch_bounds__(256) void k_rescore(
    const float* __restrict__ x, const float* __restrict__ w,
    const float* __restrict__ bn, const int* __restrict__ candc,
    const unsigned short* __restrict__ cands, float* __restrict__ out_idx) {
    const int lane = threadIdx.x & 63;
    const int n    = blockIdx.x * 4 + (threadIdx.x >> 6);   // wave -> row

    float4 xv[16];
    const float4* xr = (const float4*)(x + (size_t)n * D_DIM);
#pragma unroll
    for (int i = 0; i < 16; ++i) xv[i] = xr[i];

    // A_n: numpy-exact sum of pre-rounded squares (identical on all lanes)
    float A;
    {
        float sq[64];
#pragma unroll
        for (int i = 0; i < 16; ++i) {
            sq[4*i+0] = __fmul_rn(xv[i].x, xv[i].x);
            sq[4*i+1] = __fmul_rn(xv[i].y, xv[i].y);
            sq[4*i+2] = __fmul_rn(xv[i].z, xv[i].z);
            sq[4*i+3] = __fmul_rn(xv[i].w, xv[i].w);
        }
        A = np_pairwise64(sq);
    }

    const int cnt = candc[n];
    float bd = 3.4e38f;
    int   bi = 0x7fffffff;

    if (cnt <= CAP) {
        if (lane < cnt) {
            const int c = cands[(size_t)n * CAP + lane];
            bd = np_dist(xv, A, w, bn, c);
            bi = c;
        }
    } else {
        // wave-parallel exact full scan: lane covers c = t*64 + lane
        for (int t = 0; t < 64; ++t) {
            const int c = t * 64 + lane;
            float d = np_dist(xv, A, w, bn, c);
            if (d < bd || (d == bd && c < bi)) { bd = d; bi = c; }
        }
    }

    // lexicographic (d, idx) min across 64 lanes
#pragma unroll
    for (int m = 1; m < 64; m <<= 1) {
        float od = __shfl_xor(bd, m);
        int   oi = __shfl_xor(bi, m);
        if (od < bd || (od == bd && oi < bi)) { bd = od; bi = oi; }
    }
    if (lane == 0) out_idx[n] = (float)bi;
}

// ---- gather + STE + loss partials + segment sums (element-per-thread, ---
// ---- coalesced: R14's row-per-thread fusion was 13x slower)          ---
__global__ __launch_bounds__(256) void k_quant(
    const float* __restrict__ x, const float* __restrict__ w,
    const float* __restrict__ idxf, float* __restrict__ out0,
    float* __restrict__ sums, int* __restrict__ counts,
    double* __restrict__ lpart) {
    const int gid = blockIdx.x * 256 + threadIdx.x;
    const int n = gid >> 6, d = gid & 63;
    const int idx = (int)idxf[n];
    const float in = x[gid];
    const float q  = w[idx * D_DIM + d];
    out0[gid] = in + (q - in);               // straight-through
    const float diff = in - q;
    atomicAdd(&sums[idx * D_DIM + d], in);
    if (d == 0) atomicAdd(&counts[idx], 1);

    __shared__ double red[256];
    red[threadIdx.x] = (double)diff * (double)diff;
    __syncthreads();
    for (int s = 128; s > 0; s >>= 1) {
        if (threadIdx.x < s) red[threadIdx.x] += red[threadIdx.x + s];
        __syncthreads();
    }
    if (threadIdx.x == 0) lpart[blockIdx.x] = red[0];
}

// -------------------- loss finalize (deterministic) ----------------------
__global__ void k_loss(const double* __restrict__ lpart, float* __restrict__ out1) {
    __shared__ double red[256];
    double s = 0.0;
    for (int i = threadIdx.x; i < 8192; i += 256) s += lpart[i];
    red[threadIdx.x] = s;
    __syncthreads();
    for (int st = 128; st > 0; st >>= 1) {
        if (threadIdx.x < st) red[threadIdx.x] += red[threadIdx.x + st];
        __syncthreads();
    }
    if (threadIdx.x == 0) out1[0] = (float)(0.25 * red[0] / (double)NELEM);
}

// -------------------- ema_cs + partial sums for n ------------------------
__global__ void k_emacs(const float* __restrict__ old_cs, const int* __restrict__ counts,
                        float* __restrict__ out4, double* __restrict__ cspart) {
    const int k = blockIdx.x * 256 + threadIdx.x;
    const float e = 0.99f * old_cs[k] + 0.01f * (float)counts[k];
    out4[k] = e;
    __shared__ double red[256];
    red[threadIdx.x] = (double)e;
    __syncthreads();
    for (int s = 128; s > 0; s >>= 1) {
        if (threadIdx.x < s) red[threadIdx.x] += red[threadIdx.x + s];
        __syncthreads();
    }
    if (threadIdx.x == 0) cspart[blockIdx.x] = red[0];
}

// -------------------- ema_es + new_weight --------------------------------
__global__ __launch_bounds__(256) void k_final(
    const float* __restrict__ old_es, const float* __restrict__ sums,
    const float* __restrict__ out4, const double* __restrict__ cspart,
    float* __restrict__ out3, float* __restrict__ out5) {
    double nd = 0.0;
#pragma unroll
    for (int i = 0; i < 16; ++i) nd += cspart[i];
    const float nf = (float)nd;
    const int gid = blockIdx.x * 256 + threadIdx.x;
    const int k = gid >> 6;
    const float es = 0.99f * old_es[gid] + 0.01f * sums[gid];
    out5[gid] = es;
    const float cs = out4[k];
    const float cssm = (cs + 1e-5f) / (nf + 4096.0f * 1e-5f) * nf;
    out3[gid] = es / cssm;
}

extern "C" void kernel_launch(void* const* d_in, const int* in_sizes, int n_in,
                              void* d_out, int out_size, void* d_ws, size_t ws_size,
                              hipStream_t stream) {
    const float* x      = (const float*)d_in[0];
    const float* w      = (const float*)d_in[1];
    const float* old_cs = (const float*)d_in[2];
    const float* old_es = (const float*)d_in[3];

    float* o    = (float*)d_out;
    float* out0 = o + OUT0_OFF;
    float* out1 = o + OUT1_OFF;
    float* out2 = o + OUT2_OFF;
    float* out3 = o + OUT3_OFF;
    float* out4 = o + OUT4_OFF;
    float* out5 = o + OUT5_OFF;

    char* ws = (char*)d_ws;
    float*          bnorm  = (float*)(ws + WS_BNORM);
    int*            counts = (int*)(ws + WS_COUNTS);
    int*            candc  = (int*)(ws + WS_CANDC);
    unsigned short* cands  = (unsigned short*)(ws + WS_CANDS);
    short*          wbf    = (short*)(ws + WS_WBF);
    float*          sums   = (float*)(ws + WS_SUMS);
    double*         lpart  = (double*)(ws + WS_LPART);
    double*         cspart = (double*)(ws + WS_CSPART);

    k_prep<<<K_CODES / 256, 256, 0, stream>>>(w, bnorm, wbf, counts, candc);
    k_score<<<2048, 256, 0, stream>>>(x, wbf, bnorm, candc, cands);
    // sums overlays wbf (dead after k_score): zero it now, before k_quant
    hipMemsetAsync(sums, 0, K_CODES * D_DIM * sizeof(float), stream);
    k_rescore<<<N_VEC / 4, 256, 0, stream>>>(x, w, bnorm, candc, cands, out2);
    k_quant<<<NELEM / 256, 256, 0, stream>>>(x, w, out2, out0, sums, counts, lpart);
    k_loss<<<1, 256, 0, stream>>>(lpart, out1);
    k_emacs<<<K_CODES / 256, 256, 0, stream>>>(old_cs, counts, out4, cspart);
    k_final<<<K_CODES * D_DIM / 256, 256, 0, stream>>>(old_es, sums, out4, cspart,
                                                       out3, out5);
}